// Round 1
// baseline (2469.719 us; speedup 1.0000x reference)
//
#include <hip/hip_runtime.h>
#include <hip/hip_bf16.h>
#include <math.h>

#define N_    8
#define M_    49152
#define FIN_  64
#define K_    6
#define OUT_  64
#define E_    393216
#define ROW_  512   // FIN_*N_ floats per node row

// A[m][n][f] = x[n][m][f], vectorized as float4 (f4 = f/4)
__global__ void permute_kernel(const float* __restrict__ x, float* __restrict__ A) {
    int idx = blockIdx.x * blockDim.x + threadIdx.x;   // over M_*N_*16 float4s
    int f4 = idx & 15;
    int n  = (idx >> 4) & 7;
    int m  = idx >> 7;
    const float4* x4 = (const float4*)x;
    float4 v = x4[(size_t)(n * M_ + m) * 16 + f4];
    ((float4*)A)[idx] = v;
}

__global__ void count_kernel(const int* __restrict__ rows, int* __restrict__ cnt) {
    int e = blockIdx.x * blockDim.x + threadIdx.x;
    if (e < E_) atomicAdd(&cnt[rows[e]], 1);
}

// Single-workgroup exclusive scan over M_ counts -> rowptr[0..M_], and
// overwrite cntfill with the exclusive offsets (fill cursor array).
__global__ void scan_kernel(int* __restrict__ cntfill, int* __restrict__ rowptr) {
    __shared__ int lds[1024];
    int t = threadIdx.x;
    int base = 0;
    for (int chunk = 0; chunk < M_; chunk += 1024) {
        int v = cntfill[chunk + t];
        lds[t] = v;
        __syncthreads();
        for (int off = 1; off < 1024; off <<= 1) {
            int a = (t >= off) ? lds[t - off] : 0;
            __syncthreads();
            lds[t] += a;
            __syncthreads();
        }
        int incl = lds[t];
        int excl = base + incl - v;
        rowptr[chunk + t]  = excl;
        cntfill[chunk + t] = excl;
        base += lds[1023];
        __syncthreads();
    }
    if (t == 0) rowptr[M_] = base;
}

__global__ void fill_kernel(const int* __restrict__ rows, const int* __restrict__ cols,
                            const float* __restrict__ vals, int* __restrict__ fillpos,
                            int* __restrict__ ecol, float* __restrict__ evalv,
                            int* __restrict__ eidx) {
    int e = blockIdx.x * blockDim.x + threadIdx.x;
    if (e < E_) {
        int r = rows[e];
        int p = atomicAdd(&fillpos[r], 1);
        ecol[p]  = cols[e];
        evalv[p] = vals[e];
        eidx[p]  = e;
    }
}

// Deterministic order: insertion-sort each row segment by original edge index.
__global__ void sort_kernel(const int* __restrict__ rowptr, int* __restrict__ ecol,
                            float* __restrict__ evalv, int* __restrict__ eidx) {
    int m = blockIdx.x * blockDim.x + threadIdx.x;
    if (m >= M_) return;
    int s = rowptr[m], e = rowptr[m + 1];
    for (int i = s + 1; i < e; ++i) {
        int ki = eidx[i]; int kc = ecol[i]; float kv = evalv[i];
        int j = i - 1;
        while (j >= s && eidx[j] > ki) {
            eidx[j + 1] = eidx[j]; ecol[j + 1] = ecol[j]; evalv[j + 1] = evalv[j];
            --j;
        }
        eidx[j + 1] = ki; ecol[j + 1] = kc; evalv[j + 1] = kv;
    }
}

// One block (512 threads) per node row m.
// Phase A: stage cur[m] to LDS; SPMM: nxt[m] = alpha*(L·cur)[m] + beta*nxt[m] (in-place prev).
// Phase B: out[n,m,:] (+)= cur[m][n][:] · Wk ; optional bias+ELU on last step.
// flags: 1 = init out (write, no read), 2 = final (bias + elu), 4 = do spmm
__global__ __launch_bounds__(512) void step_kernel(
        const float* __restrict__ cur, float* __restrict__ nxt,
        const float* __restrict__ weight, const float* __restrict__ bias,
        const int* __restrict__ rowptr, const int* __restrict__ ecol,
        const float* __restrict__ evalv, float* __restrict__ out,
        int k, float alpha, float beta, int flags) {
    __shared__ float lds_x[ROW_];
    int m = blockIdx.x;
    int t = threadIdx.x;
    const float* currow = cur + (size_t)m * ROW_;
    lds_x[t] = currow[t];

    if (flags & 4) {
        float acc = 0.f;
        int s = rowptr[m], e = rowptr[m + 1];
        for (int i = s; i < e; ++i) {
            int c   = ecol[i];
            float v = evalv[i];
            acc += v * cur[(size_t)c * ROW_ + t];
        }
        float prevv = (beta != 0.f) ? nxt[(size_t)m * ROW_ + t] : 0.f;
        nxt[(size_t)m * ROW_ + t] = alpha * acc + beta * prevv;
    }
    __syncthreads();

    // dense: thread (n = t>>6, o = t&63); acc over f of lds_x[n*64+f] * W[(f*K+k)*64+o]
    int n = t >> 6, o = t & 63;
    const float4* lx4 = (const float4*)(lds_x + n * FIN_);
    float acc = 0.f;
    #pragma unroll
    for (int f4 = 0; f4 < 16; ++f4) {
        float4 xq = lx4[f4];
        int fb = f4 * 4;
        acc += xq.x * weight[((fb + 0) * K_ + k) * OUT_ + o];
        acc += xq.y * weight[((fb + 1) * K_ + k) * OUT_ + o];
        acc += xq.z * weight[((fb + 2) * K_ + k) * OUT_ + o];
        acc += xq.w * weight[((fb + 3) * K_ + k) * OUT_ + o];
    }
    size_t oidx = (size_t)n * (M_ * OUT_) + (size_t)m * OUT_ + o;
    float res = (flags & 1) ? acc : (out[oidx] + acc);
    if (flags & 2) {
        res += bias[o];
        res = (res > 0.f) ? res : (expf(res) - 1.f);
    }
    out[oidx] = res;
}

extern "C" void kernel_launch(void* const* d_in, const int* in_sizes, int n_in,
                              void* d_out, int out_size, void* d_ws, size_t ws_size,
                              hipStream_t stream) {
    (void)in_sizes; (void)n_in; (void)out_size; (void)ws_size;
    const float* x      = (const float*)d_in[0];
    const int*   rows   = (const int*)d_in[1];
    const int*   cols   = (const int*)d_in[2];
    const float* vals   = (const float*)d_in[3];
    const float* weight = (const float*)d_in[4];
    const float* bias   = (const float*)d_in[5];
    float* out = (float*)d_out;

    char* ws = (char*)d_ws;
    size_t off = 0;
    auto alloc = [&](size_t bytes) -> void* {
        void* p = ws + off;
        off += (bytes + 255) & ~(size_t)255;
        return p;
    };
    float* A       = (float*)alloc((size_t)M_ * ROW_ * 4);
    float* B       = (float*)alloc((size_t)M_ * ROW_ * 4);
    int*   rowptr  = (int*)alloc((size_t)(M_ + 1) * 4);
    int*   fillpos = (int*)alloc((size_t)M_ * 4);
    int*   ecol    = (int*)alloc((size_t)E_ * 4);
    float* evalv   = (float*)alloc((size_t)E_ * 4);
    int*   eidx    = (int*)alloc((size_t)E_ * 4);

    permute_kernel<<<(M_ * N_ * 16) / 256, 256, 0, stream>>>(x, A);
    hipMemsetAsync(fillpos, 0, (size_t)M_ * 4, stream);
    count_kernel<<<E_ / 256, 256, 0, stream>>>(rows, fillpos);
    scan_kernel<<<1, 1024, 0, stream>>>(fillpos, rowptr);
    fill_kernel<<<E_ / 256, 256, 0, stream>>>(rows, cols, vals, fillpos, ecol, evalv, eidx);
    sort_kernel<<<M_ / 256, 256, 0, stream>>>(rowptr, ecol, evalv, eidx);

    // k=0: out = T0·W0            ; B = L·A
    step_kernel<<<M_, 512, 0, stream>>>(A, B, weight, bias, rowptr, ecol, evalv, out,
                                        0, 1.f, 0.f, 1 | 4);
    // k=1: out += T1·W1           ; A = 2·L·B - A
    step_kernel<<<M_, 512, 0, stream>>>(B, A, weight, bias, rowptr, ecol, evalv, out,
                                        1, 2.f, -1.f, 4);
    // k=2: out += T2·W2           ; B = 2·L·A - B
    step_kernel<<<M_, 512, 0, stream>>>(A, B, weight, bias, rowptr, ecol, evalv, out,
                                        2, 2.f, -1.f, 4);
    // k=3
    step_kernel<<<M_, 512, 0, stream>>>(B, A, weight, bias, rowptr, ecol, evalv, out,
                                        3, 2.f, -1.f, 4);
    // k=4
    step_kernel<<<M_, 512, 0, stream>>>(A, B, weight, bias, rowptr, ecol, evalv, out,
                                        4, 2.f, -1.f, 4);
    // k=5: out = elu(out + T5·W5 + bias)   (no spmm)
    step_kernel<<<M_, 512, 0, stream>>>(B, B, weight, bias, rowptr, ecol, evalv, out,
                                        5, 0.f, 0.f, 2);
}

// Round 2
// 828.342 us; speedup vs baseline: 2.9815x; 2.9815x over previous
//
#include <hip/hip_runtime.h>
#include <hip/hip_bf16.h>
#include <math.h>

#define N_    8
#define M_    49152
#define FIN_  64
#define K_    6
#define OUT_  64
#define E_    393216
#define ROW_  512   // FIN_*N_ elements per node row

typedef __attribute__((ext_vector_type(8))) short bf16x8;
typedef __attribute__((ext_vector_type(4))) float f32x4;

static __device__ __forceinline__ unsigned short f2bf(float f) {
    unsigned u = __float_as_uint(f);
    u += 0x7fff + ((u >> 16) & 1);   // RNE
    return (unsigned short)(u >> 16);
}
static __device__ __forceinline__ float bfl(unsigned u) { return __uint_as_float(u << 16); }
static __device__ __forceinline__ float bfh(unsigned u) { return __uint_as_float(u & 0xffff0000u); }

// ---------------- CSR build (shared by both paths) ----------------

__global__ void count_kernel(const int* __restrict__ rows, int* __restrict__ cnt) {
    int e = blockIdx.x * blockDim.x + threadIdx.x;
    if (e < E_) atomicAdd(&cnt[rows[e]], 1);
}

__global__ void scan_kernel(int* __restrict__ cntfill, int* __restrict__ rowptr) {
    __shared__ int lds[1024];
    int t = threadIdx.x;
    int base = 0;
    for (int chunk = 0; chunk < M_; chunk += 1024) {
        int v = cntfill[chunk + t];
        lds[t] = v;
        __syncthreads();
        for (int off = 1; off < 1024; off <<= 1) {
            int a = (t >= off) ? lds[t - off] : 0;
            __syncthreads();
            lds[t] += a;
            __syncthreads();
        }
        int incl = lds[t];
        int excl = base + incl - v;
        rowptr[chunk + t]  = excl;
        cntfill[chunk + t] = excl;
        base += lds[1023];
        __syncthreads();
    }
    if (t == 0) rowptr[M_] = base;
}

__global__ void fill_kernel(const int* __restrict__ rows, const int* __restrict__ cols,
                            const float* __restrict__ vals, int* __restrict__ fillpos,
                            int* __restrict__ ecol, float* __restrict__ evalv,
                            int* __restrict__ eidx) {
    int e = blockIdx.x * blockDim.x + threadIdx.x;
    if (e < E_) {
        int r = rows[e];
        int p = atomicAdd(&fillpos[r], 1);
        ecol[p]  = cols[e];
        evalv[p] = vals[e];
        eidx[p]  = e;
    }
}

__global__ void sort_kernel(const int* __restrict__ rowptr, int* __restrict__ ecol,
                            float* __restrict__ evalv, int* __restrict__ eidx) {
    int m = blockIdx.x * blockDim.x + threadIdx.x;
    if (m >= M_) return;
    int s = rowptr[m], e = rowptr[m + 1];
    for (int i = s + 1; i < e; ++i) {
        int ki = eidx[i]; int kc = ecol[i]; float kv = evalv[i];
        int j = i - 1;
        while (j >= s && eidx[j] > ki) {
            eidx[j + 1] = eidx[j]; ecol[j + 1] = ecol[j]; evalv[j + 1] = evalv[j];
            --j;
        }
        eidx[j + 1] = ki; ecol[j + 1] = kc; evalv[j + 1] = kv;
    }
}

// ---------------- New bf16 path ----------------

// T0[m][n*64+f] = bf16(x[n][m][f])
__global__ void permute_bf16_kernel(const float* __restrict__ x, unsigned short* __restrict__ T0) {
    int idx = blockIdx.x * blockDim.x + threadIdx.x;   // M_*N_*16
    int f4 = idx & 15, n = (idx >> 4) & 7, m = idx >> 7;
    float4 v = ((const float4*)x)[(size_t)(n * M_ + m) * 16 + f4];
    ushort4 o;
    o.x = f2bf(v.x); o.y = f2bf(v.y); o.z = f2bf(v.z); o.w = f2bf(v.w);
    *(ushort4*)(T0 + (size_t)m * ROW_ + n * 64 + f4 * 4) = o;
}

// nxt[m] = alpha * (L @ cur)[m] + beta * prev[m]   (all bf16 storage, f32 math)
__global__ __launch_bounds__(256) void spmm_bf16_kernel(
        const unsigned short* __restrict__ cur, const unsigned short* __restrict__ prev,
        unsigned short* __restrict__ nxt,
        const int* __restrict__ rowptr, const int* __restrict__ ecol,
        const float* __restrict__ evalv, float alpha, float beta) {
    int m = blockIdx.x, t = threadIdx.x;
    int s = rowptr[m], e = rowptr[m + 1];
    float ax = 0.f, ay = 0.f;
    for (int i = s; i < e; ++i) {
        int c = ecol[i];
        float v = evalv[i];
        unsigned u = *(const unsigned*)(cur + (size_t)c * ROW_ + t * 2);
        ax += v * bfl(u);
        ay += v * bfh(u);
    }
    float rx = alpha * ax, ry = alpha * ay;
    if (beta != 0.f) {
        unsigned p = *(const unsigned*)(prev + (size_t)m * ROW_ + t * 2);
        rx += beta * bfl(p);
        ry += beta * bfh(p);
    }
    unsigned o = (unsigned)f2bf(rx) | ((unsigned)f2bf(ry) << 16);
    *(unsigned*)(nxt + (size_t)m * ROW_ + t * 2) = o;
}

// Wfrag[kk][tile][lane][i] = bf16(W[f*K+kcheb][tile*16 + lane%16]),
//   kcheb = kk>>1, f = (kk&1)*32 + (lane>>4)*8 + i   (B-fragment order for 16x16x32)
__global__ void wprep_kernel(const float* __restrict__ W, unsigned short* __restrict__ Wfrag) {
    int idx = blockIdx.x * blockDim.x + threadIdx.x;   // 12*4*64*8 = 24576
    int i = idx & 7, l = (idx >> 3) & 63, tile = (idx >> 9) & 3, kk = idx >> 11;
    int kcheb = kk >> 1;
    int f = (kk & 1) * 32 + (l >> 4) * 8 + i;
    int o = tile * 16 + (l & 15);
    Wfrag[idx] = f2bf(W[(f * K_ + kcheb) * OUT_ + o]);
}

static __device__ __forceinline__ void epilogue_tile(
        f32x4 acc, int tile, int rbase, int col,
        const float* __restrict__ bias, float* __restrict__ outn) {
    int c = tile * 16 + col;
    float b = bias[c];
    #pragma unroll
    for (int v = 0; v < 4; ++v) {
        float r = acc[v] + b;
        r = r > 0.f ? r : (expf(r) - 1.f);
        outn[(size_t)(rbase + v) * OUT_ + c] = r;
    }
}

// out[n][m][o] = elu( sum_{k,f} T_k[m][n*64+f] * W[f*K+k][o] + bias[o] )
// grid (M_/64, 8), block 256 (4 waves). Wave w: rows bm*64+w*16 .. +15, all 64 cols.
__global__ __launch_bounds__(256) void combine_kernel(
        const unsigned short* __restrict__ Tbase,   // 6 buffers, stride M_*ROW_
        const unsigned short* __restrict__ Wfrag,
        const float* __restrict__ bias, float* __restrict__ out) {
    int n  = blockIdx.y;
    int bm = blockIdx.x;
    int t  = threadIdx.x;
    int w = t >> 6, l = t & 63;
    int m0 = bm * 64 + w * 16;
    int arow = m0 + (l & 15);
    size_t abase = (size_t)arow * ROW_ + n * 64 + (l >> 4) * 8;

    f32x4 acc0 = {0.f, 0.f, 0.f, 0.f};
    f32x4 acc1 = {0.f, 0.f, 0.f, 0.f};
    f32x4 acc2 = {0.f, 0.f, 0.f, 0.f};
    f32x4 acc3 = {0.f, 0.f, 0.f, 0.f};

    #pragma unroll
    for (int kk = 0; kk < 12; ++kk) {
        const unsigned short* Tk = Tbase + (size_t)(kk >> 1) * ((size_t)M_ * ROW_);
        bf16x8 a = *(const bf16x8*)(Tk + abase + (kk & 1) * 32);
        const unsigned short* wp = Wfrag + ((size_t)(kk * 4) * 64 + l) * 8;
        bf16x8 b0 = *(const bf16x8*)(wp);
        bf16x8 b1 = *(const bf16x8*)(wp + 64 * 8);
        bf16x8 b2 = *(const bf16x8*)(wp + 2 * 64 * 8);
        bf16x8 b3 = *(const bf16x8*)(wp + 3 * 64 * 8);
        acc0 = __builtin_amdgcn_mfma_f32_16x16x32_bf16(a, b0, acc0, 0, 0, 0);
        acc1 = __builtin_amdgcn_mfma_f32_16x16x32_bf16(a, b1, acc1, 0, 0, 0);
        acc2 = __builtin_amdgcn_mfma_f32_16x16x32_bf16(a, b2, acc2, 0, 0, 0);
        acc3 = __builtin_amdgcn_mfma_f32_16x16x32_bf16(a, b3, acc3, 0, 0, 0);
    }

    float* outn = out + (size_t)n * ((size_t)M_ * OUT_);
    int rbase = m0 + (l >> 4) * 4;
    int col = l & 15;
    epilogue_tile(acc0, 0, rbase, col, bias, outn);
    epilogue_tile(acc1, 1, rbase, col, bias, outn);
    epilogue_tile(acc2, 2, rbase, col, bias, outn);
    epilogue_tile(acc3, 3, rbase, col, bias, outn);
}

// ---------------- Fallback f32 fused path (if ws too small) ----------------

__global__ void permute_kernel(const float* __restrict__ x, float* __restrict__ A) {
    int idx = blockIdx.x * blockDim.x + threadIdx.x;
    int f4 = idx & 15;
    int n  = (idx >> 4) & 7;
    int m  = idx >> 7;
    float4 v = ((const float4*)x)[(size_t)(n * M_ + m) * 16 + f4];
    ((float4*)A)[idx] = v;
}

__global__ __launch_bounds__(512) void step_kernel(
        const float* __restrict__ cur, float* __restrict__ nxt,
        const float* __restrict__ weight, const float* __restrict__ bias,
        const int* __restrict__ rowptr, const int* __restrict__ ecol,
        const float* __restrict__ evalv, float* __restrict__ out,
        int k, float alpha, float beta, int flags) {
    __shared__ float lds_x[ROW_];
    int m = blockIdx.x;
    int t = threadIdx.x;
    lds_x[t] = cur[(size_t)m * ROW_ + t];
    if (flags & 4) {
        float acc = 0.f;
        int s = rowptr[m], e = rowptr[m + 1];
        for (int i = s; i < e; ++i)
            acc += evalv[i] * cur[(size_t)ecol[i] * ROW_ + t];
        float prevv = (beta != 0.f) ? nxt[(size_t)m * ROW_ + t] : 0.f;
        nxt[(size_t)m * ROW_ + t] = alpha * acc + beta * prevv;
    }
    __syncthreads();
    int n = t >> 6, o = t & 63;
    const float4* lx4 = (const float4*)(lds_x + n * FIN_);
    float acc = 0.f;
    #pragma unroll
    for (int f4 = 0; f4 < 16; ++f4) {
        float4 xq = lx4[f4];
        int fb = f4 * 4;
        acc += xq.x * weight[((fb + 0) * K_ + k) * OUT_ + o];
        acc += xq.y * weight[((fb + 1) * K_ + k) * OUT_ + o];
        acc += xq.z * weight[((fb + 2) * K_ + k) * OUT_ + o];
        acc += xq.w * weight[((fb + 3) * K_ + k) * OUT_ + o];
    }
    size_t oidx = (size_t)n * (M_ * OUT_) + (size_t)m * OUT_ + o;
    float res = (flags & 1) ? acc : (out[oidx] + acc);
    if (flags & 2) {
        res += bias[o];
        res = (res > 0.f) ? res : (expf(res) - 1.f);
    }
    out[oidx] = res;
}

// ---------------- launch ----------------

extern "C" void kernel_launch(void* const* d_in, const int* in_sizes, int n_in,
                              void* d_out, int out_size, void* d_ws, size_t ws_size,
                              hipStream_t stream) {
    (void)in_sizes; (void)n_in; (void)out_size;
    const float* x      = (const float*)d_in[0];
    const int*   rows   = (const int*)d_in[1];
    const int*   cols   = (const int*)d_in[2];
    const float* vals   = (const float*)d_in[3];
    const float* weight = (const float*)d_in[4];
    const float* bias   = (const float*)d_in[5];
    float* out = (float*)d_out;

    char* ws = (char*)d_ws;
    size_t off = 0;
    auto alloc = [&](size_t bytes) -> void* {
        void* p = ws + off;
        off += (bytes + 255) & ~(size_t)255;
        return p;
    };

    const size_t tbytes = (size_t)M_ * ROW_ * 2;          // 50.3 MB per bf16 T buffer
    const size_t need_new = 6 * (tbytes + 256) + (M_ + 1) * 4 + M_ * 4
                          + 3 * ((size_t)E_ * 4 + 256) + 24576 * 2 + 4096;

    if (ws_size >= need_new) {
        unsigned short* T[6];
        for (int i = 0; i < 6; ++i) T[i] = (unsigned short*)alloc(tbytes);
        int*   rowptr  = (int*)alloc((size_t)(M_ + 1) * 4);
        int*   fillpos = (int*)alloc((size_t)M_ * 4);
        int*   ecol    = (int*)alloc((size_t)E_ * 4);
        float* evalv   = (float*)alloc((size_t)E_ * 4);
        int*   eidx    = (int*)alloc((size_t)E_ * 4);
        unsigned short* Wfrag = (unsigned short*)alloc(24576 * 2);

        permute_bf16_kernel<<<(M_ * N_ * 16) / 256, 256, 0, stream>>>(x, T[0]);
        hipMemsetAsync(fillpos, 0, (size_t)M_ * 4, stream);
        count_kernel<<<E_ / 256, 256, 0, stream>>>(rows, fillpos);
        scan_kernel<<<1, 1024, 0, stream>>>(fillpos, rowptr);
        fill_kernel<<<E_ / 256, 256, 0, stream>>>(rows, cols, vals, fillpos, ecol, evalv, eidx);
        sort_kernel<<<M_ / 256, 256, 0, stream>>>(rowptr, ecol, evalv, eidx);
        wprep_kernel<<<96, 256, 0, stream>>>(weight, Wfrag);

        // T1 = L T0 ; Tk = 2 L T_{k-1} - T_{k-2}
        spmm_bf16_kernel<<<M_, 256, 0, stream>>>(T[0], T[0], T[1], rowptr, ecol, evalv, 1.f, 0.f);
        spmm_bf16_kernel<<<M_, 256, 0, stream>>>(T[1], T[0], T[2], rowptr, ecol, evalv, 2.f, -1.f);
        spmm_bf16_kernel<<<M_, 256, 0, stream>>>(T[2], T[1], T[3], rowptr, ecol, evalv, 2.f, -1.f);
        spmm_bf16_kernel<<<M_, 256, 0, stream>>>(T[3], T[2], T[4], rowptr, ecol, evalv, 2.f, -1.f);
        spmm_bf16_kernel<<<M_, 256, 0, stream>>>(T[4], T[3], T[5], rowptr, ecol, evalv, 2.f, -1.f);

        combine_kernel<<<dim3(M_ / 64, 8), 256, 0, stream>>>(T[0], Wfrag, bias, out);
    } else {
        float* A       = (float*)alloc((size_t)M_ * ROW_ * 4);
        float* B       = (float*)alloc((size_t)M_ * ROW_ * 4);
        int*   rowptr  = (int*)alloc((size_t)(M_ + 1) * 4);
        int*   fillpos = (int*)alloc((size_t)M_ * 4);
        int*   ecol    = (int*)alloc((size_t)E_ * 4);
        float* evalv   = (float*)alloc((size_t)E_ * 4);
        int*   eidx    = (int*)alloc((size_t)E_ * 4);

        permute_kernel<<<(M_ * N_ * 16) / 256, 256, 0, stream>>>(x, A);
        hipMemsetAsync(fillpos, 0, (size_t)M_ * 4, stream);
        count_kernel<<<E_ / 256, 256, 0, stream>>>(rows, fillpos);
        scan_kernel<<<1, 1024, 0, stream>>>(fillpos, rowptr);
        fill_kernel<<<E_ / 256, 256, 0, stream>>>(rows, cols, vals, fillpos, ecol, evalv, eidx);
        sort_kernel<<<M_ / 256, 256, 0, stream>>>(rowptr, ecol, evalv, eidx);

        step_kernel<<<M_, 512, 0, stream>>>(A, B, weight, bias, rowptr, ecol, evalv, out, 0, 1.f, 0.f, 1 | 4);
        step_kernel<<<M_, 512, 0, stream>>>(B, A, weight, bias, rowptr, ecol, evalv, out, 1, 2.f, -1.f, 4);
        step_kernel<<<M_, 512, 0, stream>>>(A, B, weight, bias, rowptr, ecol, evalv, out, 2, 2.f, -1.f, 4);
        step_kernel<<<M_, 512, 0, stream>>>(B, A, weight, bias, rowptr, ecol, evalv, out, 3, 2.f, -1.f, 4);
        step_kernel<<<M_, 512, 0, stream>>>(A, B, weight, bias, rowptr, ecol, evalv, out, 4, 2.f, -1.f, 4);
        step_kernel<<<M_, 512, 0, stream>>>(B, B, weight, bias, rowptr, ecol, evalv, out, 5, 0.f, 0.f, 2);
    }
}

// Round 3
// 594.987 us; speedup vs baseline: 4.1509x; 1.3922x over previous
//
#include <hip/hip_runtime.h>
#include <hip/hip_bf16.h>
#include <math.h>

#define N_    8
#define M_    49152
#define FIN_  64
#define K_    6
#define OUT_  64
#define E_    393216
#define ROW_  512   // FIN_*N_ elements per node row

typedef __attribute__((ext_vector_type(8))) short bf16x8;
typedef __attribute__((ext_vector_type(4))) float f32x4;

static __device__ __forceinline__ unsigned short f2bf(float f) {
    unsigned u = __float_as_uint(f);
    u += 0x7fff + ((u >> 16) & 1);   // RNE
    return (unsigned short)(u >> 16);
}
static __device__ __forceinline__ float bfl(unsigned u) { return __uint_as_float(u << 16); }
static __device__ __forceinline__ float bfh(unsigned u) { return __uint_as_float(u & 0xffff0000u); }

// ---------------- CSR build ----------------

__global__ void count_kernel(const int* __restrict__ rows, int* __restrict__ cnt) {
    int e = blockIdx.x * blockDim.x + threadIdx.x;
    if (e < E_) atomicAdd(&cnt[rows[e]], 1);
}

// Single-block scan, wave-parallel: shfl_up wave scans + serial 16-wavesum scan.
__global__ __launch_bounds__(1024) void scan_kernel(int* __restrict__ cntfill, int* __restrict__ rowptr) {
    __shared__ int wsum[16];
    __shared__ int carry;
    int t = threadIdx.x;
    int lane = t & 63, wid = t >> 6;
    if (t == 0) carry = 0;
    __syncthreads();
    for (int chunk = 0; chunk < M_; chunk += 1024) {
        int v = cntfill[chunk + t];
        int x = v;
        #pragma unroll
        for (int off = 1; off < 64; off <<= 1) {
            int y = __shfl_up(x, off, 64);
            if (lane >= off) x += y;
        }
        if (lane == 63) wsum[wid] = x;
        __syncthreads();
        if (t == 0) {
            int s = carry;
            #pragma unroll
            for (int i = 0; i < 16; ++i) { int c = wsum[i]; wsum[i] = s; s += c; }
            carry = s;
        }
        __syncthreads();
        int excl = wsum[wid] + x - v;   // base + wave-exclusive
        rowptr[chunk + t]  = excl;
        cntfill[chunk + t] = excl;
        __syncthreads();
    }
    if (t == 0) rowptr[M_] = carry;
}

__global__ void fill_kernel(const int* __restrict__ rows, const int* __restrict__ cols,
                            const float* __restrict__ vals, int* __restrict__ fillpos,
                            int* __restrict__ ecol, float* __restrict__ evalv,
                            int* __restrict__ eidx) {
    int e = blockIdx.x * blockDim.x + threadIdx.x;
    if (e < E_) {
        int r = rows[e];
        int p = atomicAdd(&fillpos[r], 1);
        ecol[p]  = cols[e];
        evalv[p] = vals[e];
        eidx[p]  = e;
    }
}

__global__ void sort_kernel(const int* __restrict__ rowptr, int* __restrict__ ecol,
                            float* __restrict__ evalv, int* __restrict__ eidx) {
    int m = blockIdx.x * blockDim.x + threadIdx.x;
    if (m >= M_) return;
    int s = rowptr[m], e = rowptr[m + 1];
    for (int i = s + 1; i < e; ++i) {
        int ki = eidx[i]; int kc = ecol[i]; float kv = evalv[i];
        int j = i - 1;
        while (j >= s && eidx[j] > ki) {
            eidx[j + 1] = eidx[j]; ecol[j + 1] = ecol[j]; evalv[j + 1] = evalv[j];
            --j;
        }
        eidx[j + 1] = ki; ecol[j + 1] = kc; evalv[j + 1] = kv;
    }
}

// ---------------- bf16 path ----------------

// T0[m][n*64+f] = bf16(x[n][m][f])
__global__ void permute_bf16_kernel(const float* __restrict__ x, unsigned short* __restrict__ T0) {
    int idx = blockIdx.x * blockDim.x + threadIdx.x;   // M_*N_*16
    int f4 = idx & 15, n = (idx >> 4) & 7, m = idx >> 7;
    float4 v = ((const float4*)x)[(size_t)(n * M_ + m) * 16 + f4];
    ushort4 o;
    o.x = f2bf(v.x); o.y = f2bf(v.y); o.z = f2bf(v.z); o.w = f2bf(v.w);
    *(ushort4*)(T0 + (size_t)m * ROW_ + n * 64 + f4 * 4) = o;
}

static __device__ __forceinline__ void fma_u4(float* acc, float v, uint4 u) {
    acc[0] += v * bfl(u.x); acc[1] += v * bfh(u.x);
    acc[2] += v * bfl(u.y); acc[3] += v * bfh(u.y);
    acc[4] += v * bfl(u.z); acc[5] += v * bfh(u.z);
    acc[6] += v * bfl(u.w); acc[7] += v * bfh(u.w);
}

// nxt[m] = alpha * (L @ cur)[m] + beta * prev[m]; wave w handles row blockIdx*4+w,
// lane l covers bf16 elements l*8 .. l*8+7 (16B).
__global__ __launch_bounds__(256) void spmm_bf16_kernel(
        const unsigned short* __restrict__ cur, const unsigned short* __restrict__ prev,
        unsigned short* __restrict__ nxt,
        const int* __restrict__ rowptr, const int* __restrict__ ecol,
        const float* __restrict__ evalv, float alpha, float beta) {
    int t = threadIdx.x;
    int w = t >> 6, l = t & 63;
    int m = blockIdx.x * 4 + w;
    int s = rowptr[m], e = rowptr[m + 1];
    float acc[8] = {0.f, 0.f, 0.f, 0.f, 0.f, 0.f, 0.f, 0.f};
    int i = s;
    for (; i + 1 < e; i += 2) {
        int c0 = ecol[i],     c1 = ecol[i + 1];
        float v0 = evalv[i],  v1 = evalv[i + 1];
        uint4 u0 = *(const uint4*)(cur + (size_t)c0 * ROW_ + l * 8);
        uint4 u1 = *(const uint4*)(cur + (size_t)c1 * ROW_ + l * 8);
        fma_u4(acc, v0, u0);
        fma_u4(acc, v1, u1);
    }
    if (i < e) {
        int c0 = ecol[i];
        float v0 = evalv[i];
        uint4 u0 = *(const uint4*)(cur + (size_t)c0 * ROW_ + l * 8);
        fma_u4(acc, v0, u0);
    }
    #pragma unroll
    for (int j = 0; j < 8; ++j) acc[j] *= alpha;
    if (beta != 0.f) {
        uint4 p = *(const uint4*)(prev + (size_t)m * ROW_ + l * 8);
        acc[0] += beta * bfl(p.x); acc[1] += beta * bfh(p.x);
        acc[2] += beta * bfl(p.y); acc[3] += beta * bfh(p.y);
        acc[4] += beta * bfl(p.z); acc[5] += beta * bfh(p.z);
        acc[6] += beta * bfl(p.w); acc[7] += beta * bfh(p.w);
    }
    uint4 o;
    o.x = (unsigned)f2bf(acc[0]) | ((unsigned)f2bf(acc[1]) << 16);
    o.y = (unsigned)f2bf(acc[2]) | ((unsigned)f2bf(acc[3]) << 16);
    o.z = (unsigned)f2bf(acc[4]) | ((unsigned)f2bf(acc[5]) << 16);
    o.w = (unsigned)f2bf(acc[6]) | ((unsigned)f2bf(acc[7]) << 16);
    *(uint4*)(nxt + (size_t)m * ROW_ + l * 8) = o;
}

// Wfrag[kk][tile][lane][i] = bf16(W[f*K+kcheb][tile*16 + lane%16]),
//   kcheb = kk>>1, f = (kk&1)*32 + (lane>>4)*8 + i   (B-fragment order for 16x16x32)
__global__ void wprep_kernel(const float* __restrict__ W, unsigned short* __restrict__ Wfrag) {
    int idx = blockIdx.x * blockDim.x + threadIdx.x;   // 24576
    int i = idx & 7, l = (idx >> 3) & 63, tile = (idx >> 9) & 3, kk = idx >> 11;
    int kcheb = kk >> 1;
    int f = (kk & 1) * 32 + (l >> 4) * 8 + i;
    int o = tile * 16 + (l & 15);
    Wfrag[idx] = f2bf(W[(f * K_ + kcheb) * OUT_ + o]);
}

static __device__ __forceinline__ void epilogue_tile(
        f32x4 acc, int tile, int rbase, int col,
        const float* __restrict__ bias, float* __restrict__ outn) {
    int c = tile * 16 + col;
    float b = bias[c];
    #pragma unroll
    for (int v = 0; v < 4; ++v) {
        float r = acc[v] + b;
        r = r > 0.f ? r : (__expf(r) - 1.f);
        outn[(size_t)(rbase + v) * OUT_ + c] = r;
    }
}

// out[n][m][o] = elu( sum_{k,f} T_k[m][n*64+f] * W[f*K+k][o] + bias[o] )
// grid (M_/64, 8), block 256 (4 waves). Wave w: rows bm*64+w*16 .. +15, all 64 cols.
// All 12 A-fragments preloaded into registers to batch the global-load latency.
__global__ __launch_bounds__(256) void combine_kernel(
        const unsigned short* __restrict__ Tbase,   // 6 buffers, stride M_*ROW_
        const unsigned short* __restrict__ Wfrag,
        const float* __restrict__ bias, float* __restrict__ out) {
    int n  = blockIdx.y;
    int bm = blockIdx.x;
    int t  = threadIdx.x;
    int w = t >> 6, l = t & 63;
    int m0 = bm * 64 + w * 16;
    int arow = m0 + (l & 15);
    size_t abase = (size_t)arow * ROW_ + n * 64 + (l >> 4) * 8;
    const size_t MROW = (size_t)M_ * ROW_;

    bf16x8 a[12];
    #pragma unroll
    for (int kk = 0; kk < 12; ++kk) {
        const unsigned short* Tk = Tbase + (size_t)(kk >> 1) * MROW;
        a[kk] = *(const bf16x8*)(Tk + abase + (kk & 1) * 32);
    }

    f32x4 acc0 = {0.f, 0.f, 0.f, 0.f};
    f32x4 acc1 = {0.f, 0.f, 0.f, 0.f};
    f32x4 acc2 = {0.f, 0.f, 0.f, 0.f};
    f32x4 acc3 = {0.f, 0.f, 0.f, 0.f};

    #pragma unroll
    for (int kk = 0; kk < 12; ++kk) {
        const unsigned short* wp = Wfrag + ((size_t)(kk * 4) * 64 + l) * 8;
        bf16x8 b0 = *(const bf16x8*)(wp);
        bf16x8 b1 = *(const bf16x8*)(wp + 64 * 8);
        bf16x8 b2 = *(const bf16x8*)(wp + 2 * 64 * 8);
        bf16x8 b3 = *(const bf16x8*)(wp + 3 * 64 * 8);
        acc0 = __builtin_amdgcn_mfma_f32_16x16x32_bf16(a[kk], b0, acc0, 0, 0, 0);
        acc1 = __builtin_amdgcn_mfma_f32_16x16x32_bf16(a[kk], b1, acc1, 0, 0, 0);
        acc2 = __builtin_amdgcn_mfma_f32_16x16x32_bf16(a[kk], b2, acc2, 0, 0, 0);
        acc3 = __builtin_amdgcn_mfma_f32_16x16x32_bf16(a[kk], b3, acc3, 0, 0, 0);
    }

    float* outn = out + (size_t)n * ((size_t)M_ * OUT_);
    int rbase = m0 + (l >> 4) * 4;
    int col = l & 15;
    epilogue_tile(acc0, 0, rbase, col, bias, outn);
    epilogue_tile(acc1, 1, rbase, col, bias, outn);
    epilogue_tile(acc2, 2, rbase, col, bias, outn);
    epilogue_tile(acc3, 3, rbase, col, bias, outn);
}

// ---------------- Fallback f32 fused path ----------------

__global__ void permute_kernel(const float* __restrict__ x, float* __restrict__ A) {
    int idx = blockIdx.x * blockDim.x + threadIdx.x;
    int f4 = idx & 15;
    int n  = (idx >> 4) & 7;
    int m  = idx >> 7;
    float4 v = ((const float4*)x)[(size_t)(n * M_ + m) * 16 + f4];
    ((float4*)A)[idx] = v;
}

__global__ __launch_bounds__(512) void step_kernel(
        const float* __restrict__ cur, float* __restrict__ nxt,
        const float* __restrict__ weight, const float* __restrict__ bias,
        const int* __restrict__ rowptr, const int* __restrict__ ecol,
        const float* __restrict__ evalv, float* __restrict__ out,
        int k, float alpha, float beta, int flags) {
    __shared__ float lds_x[ROW_];
    int m = blockIdx.x;
    int t = threadIdx.x;
    lds_x[t] = cur[(size_t)m * ROW_ + t];
    if (flags & 4) {
        float acc = 0.f;
        int s = rowptr[m], e = rowptr[m + 1];
        for (int i = s; i < e; ++i)
            acc += evalv[i] * cur[(size_t)ecol[i] * ROW_ + t];
        float prevv = (beta != 0.f) ? nxt[(size_t)m * ROW_ + t] : 0.f;
        nxt[(size_t)m * ROW_ + t] = alpha * acc + beta * prevv;
    }
    __syncthreads();
    int n = t >> 6, o = t & 63;
    const float4* lx4 = (const float4*)(lds_x + n * FIN_);
    float acc = 0.f;
    #pragma unroll
    for (int f4 = 0; f4 < 16; ++f4) {
        float4 xq = lx4[f4];
        int fb = f4 * 4;
        acc += xq.x * weight[((fb + 0) * K_ + k) * OUT_ + o];
        acc += xq.y * weight[((fb + 1) * K_ + k) * OUT_ + o];
        acc += xq.z * weight[((fb + 2) * K_ + k) * OUT_ + o];
        acc += xq.w * weight[((fb + 3) * K_ + k) * OUT_ + o];
    }
    size_t oidx = (size_t)n * (M_ * OUT_) + (size_t)m * OUT_ + o;
    float res = (flags & 1) ? acc : (out[oidx] + acc);
    if (flags & 2) {
        res += bias[o];
        res = (res > 0.f) ? res : (expf(res) - 1.f);
    }
    out[oidx] = res;
}

// ---------------- launch ----------------

extern "C" void kernel_launch(void* const* d_in, const int* in_sizes, int n_in,
                              void* d_out, int out_size, void* d_ws, size_t ws_size,
                              hipStream_t stream) {
    (void)in_sizes; (void)n_in; (void)out_size;
    const float* x      = (const float*)d_in[0];
    const int*   rows   = (const int*)d_in[1];
    const int*   cols   = (const int*)d_in[2];
    const float* vals   = (const float*)d_in[3];
    const float* weight = (const float*)d_in[4];
    const float* bias   = (const float*)d_in[5];
    float* out = (float*)d_out;

    char* ws = (char*)d_ws;
    size_t off = 0;
    auto alloc = [&](size_t bytes) -> void* {
        void* p = ws + off;
        off += (bytes + 255) & ~(size_t)255;
        return p;
    };

    const size_t tbytes = (size_t)M_ * ROW_ * 2;          // 50.3 MB per bf16 T buffer
    const size_t need_new = 6 * (tbytes + 256) + (M_ + 1) * 4 + M_ * 4
                          + 3 * ((size_t)E_ * 4 + 256) + 24576 * 2 + 4096;

    if (ws_size >= need_new) {
        unsigned short* T[6];
        for (int i = 0; i < 6; ++i) T[i] = (unsigned short*)alloc(tbytes);
        int*   rowptr  = (int*)alloc((size_t)(M_ + 1) * 4);
        int*   fillpos = (int*)alloc((size_t)M_ * 4);
        int*   ecol    = (int*)alloc((size_t)E_ * 4);
        float* evalv   = (float*)alloc((size_t)E_ * 4);
        int*   eidx    = (int*)alloc((size_t)E_ * 4);
        unsigned short* Wfrag = (unsigned short*)alloc(24576 * 2);

        permute_bf16_kernel<<<(M_ * N_ * 16) / 256, 256, 0, stream>>>(x, T[0]);
        hipMemsetAsync(fillpos, 0, (size_t)M_ * 4, stream);
        count_kernel<<<E_ / 256, 256, 0, stream>>>(rows, fillpos);
        scan_kernel<<<1, 1024, 0, stream>>>(fillpos, rowptr);
        fill_kernel<<<E_ / 256, 256, 0, stream>>>(rows, cols, vals, fillpos, ecol, evalv, eidx);
        sort_kernel<<<M_ / 256, 256, 0, stream>>>(rowptr, ecol, evalv, eidx);
        wprep_kernel<<<96, 256, 0, stream>>>(weight, Wfrag);

        // T1 = L T0 ; Tk = 2 L T_{k-1} - T_{k-2}
        spmm_bf16_kernel<<<M_ / 4, 256, 0, stream>>>(T[0], T[0], T[1], rowptr, ecol, evalv, 1.f, 0.f);
        spmm_bf16_kernel<<<M_ / 4, 256, 0, stream>>>(T[1], T[0], T[2], rowptr, ecol, evalv, 2.f, -1.f);
        spmm_bf16_kernel<<<M_ / 4, 256, 0, stream>>>(T[2], T[1], T[3], rowptr, ecol, evalv, 2.f, -1.f);
        spmm_bf16_kernel<<<M_ / 4, 256, 0, stream>>>(T[3], T[2], T[4], rowptr, ecol, evalv, 2.f, -1.f);
        spmm_bf16_kernel<<<M_ / 4, 256, 0, stream>>>(T[4], T[3], T[5], rowptr, ecol, evalv, 2.f, -1.f);

        combine_kernel<<<dim3(M_ / 64, 8), 256, 0, stream>>>(T[0], Wfrag, bias, out);
    } else {
        float* A       = (float*)alloc((size_t)M_ * ROW_ * 4);
        float* B       = (float*)alloc((size_t)M_ * ROW_ * 4);
        int*   rowptr  = (int*)alloc((size_t)(M_ + 1) * 4);
        int*   fillpos = (int*)alloc((size_t)M_ * 4);
        int*   ecol    = (int*)alloc((size_t)E_ * 4);
        float* evalv   = (float*)alloc((size_t)E_ * 4);
        int*   eidx    = (int*)alloc((size_t)E_ * 4);

        permute_kernel<<<(M_ * N_ * 16) / 256, 256, 0, stream>>>(x, A);
        hipMemsetAsync(fillpos, 0, (size_t)M_ * 4, stream);
        count_kernel<<<E_ / 256, 256, 0, stream>>>(rows, fillpos);
        scan_kernel<<<1, 1024, 0, stream>>>(fillpos, rowptr);
        fill_kernel<<<E_ / 256, 256, 0, stream>>>(rows, cols, vals, fillpos, ecol, evalv, eidx);
        sort_kernel<<<M_ / 256, 256, 0, stream>>>(rowptr, ecol, evalv, eidx);

        step_kernel<<<M_, 512, 0, stream>>>(A, B, weight, bias, rowptr, ecol, evalv, out, 0, 1.f, 0.f, 1 | 4);
        step_kernel<<<M_, 512, 0, stream>>>(B, A, weight, bias, rowptr, ecol, evalv, out, 1, 2.f, -1.f, 4);
        step_kernel<<<M_, 512, 0, stream>>>(A, B, weight, bias, rowptr, ecol, evalv, out, 2, 2.f, -1.f, 4);
        step_kernel<<<M_, 512, 0, stream>>>(B, A, weight, bias, rowptr, ecol, evalv, out, 3, 2.f, -1.f, 4);
        step_kernel<<<M_, 512, 0, stream>>>(A, B, weight, bias, rowptr, ecol, evalv, out, 4, 2.f, -1.f, 4);
        step_kernel<<<M_, 512, 0, stream>>>(B, B, weight, bias, rowptr, ecol, evalv, out, 5, 0.f, 0.f, 2);
    }
}

// Round 4
// 567.486 us; speedup vs baseline: 4.3520x; 1.0485x over previous
//
#include <hip/hip_runtime.h>
#include <hip/hip_bf16.h>
#include <math.h>

#define N_    8
#define M_    49152
#define FIN_  64
#define K_    6
#define OUT_  64
#define E_    393216
#define ROW_  512   // FIN_*N_ elements per node row

typedef __attribute__((ext_vector_type(8))) short bf16x8;
typedef __attribute__((ext_vector_type(4))) float f32x4;

static __device__ __forceinline__ unsigned short f2bf(float f) {
    unsigned u = __float_as_uint(f);
    u += 0x7fff + ((u >> 16) & 1);   // RNE
    return (unsigned short)(u >> 16);
}
static __device__ __forceinline__ float bfl(unsigned u) { return __uint_as_float(u << 16); }
static __device__ __forceinline__ float bfh(unsigned u) { return __uint_as_float(u & 0xffff0000u); }

// ---------------- CSR build ----------------

__global__ void count_kernel(const int* __restrict__ rows, int* __restrict__ cnt) {
    int e = blockIdx.x * blockDim.x + threadIdx.x;
    if (e < E_) atomicAdd(&cnt[rows[e]], 1);
}

// Single-block scan, wave-parallel: shfl_up wave scans + serial 16-wavesum scan.
__global__ __launch_bounds__(1024) void scan_kernel(int* __restrict__ cntfill, int* __restrict__ rowptr) {
    __shared__ int wsum[16];
    __shared__ int carry;
    int t = threadIdx.x;
    int lane = t & 63, wid = t >> 6;
    if (t == 0) carry = 0;
    __syncthreads();
    for (int chunk = 0; chunk < M_; chunk += 1024) {
        int v = cntfill[chunk + t];
        int x = v;
        #pragma unroll
        for (int off = 1; off < 64; off <<= 1) {
            int y = __shfl_up(x, off, 64);
            if (lane >= off) x += y;
        }
        if (lane == 63) wsum[wid] = x;
        __syncthreads();
        if (t == 0) {
            int s = carry;
            #pragma unroll
            for (int i = 0; i < 16; ++i) { int c = wsum[i]; wsum[i] = s; s += c; }
            carry = s;
        }
        __syncthreads();
        int excl = wsum[wid] + x - v;   // base + wave-exclusive
        rowptr[chunk + t]  = excl;
        cntfill[chunk + t] = excl;
        __syncthreads();
    }
    if (t == 0) rowptr[M_] = carry;
}

__global__ void fill_kernel(const int* __restrict__ rows, const int* __restrict__ cols,
                            const float* __restrict__ vals, int* __restrict__ fillpos,
                            int* __restrict__ ecol, float* __restrict__ evalv,
                            int* __restrict__ eidx) {
    int e = blockIdx.x * blockDim.x + threadIdx.x;
    if (e < E_) {
        int r = rows[e];
        int p = atomicAdd(&fillpos[r], 1);
        ecol[p]  = cols[e];
        evalv[p] = vals[e];
        eidx[p]  = e;
    }
}

__global__ void sort_kernel(const int* __restrict__ rowptr, int* __restrict__ ecol,
                            float* __restrict__ evalv, int* __restrict__ eidx) {
    int m = blockIdx.x * blockDim.x + threadIdx.x;
    if (m >= M_) return;
    int s = rowptr[m], e = rowptr[m + 1];
    for (int i = s + 1; i < e; ++i) {
        int ki = eidx[i]; int kc = ecol[i]; float kv = evalv[i];
        int j = i - 1;
        while (j >= s && eidx[j] > ki) {
            eidx[j + 1] = eidx[j]; ecol[j + 1] = ecol[j]; evalv[j + 1] = evalv[j];
            --j;
        }
        eidx[j + 1] = ki; ecol[j + 1] = kc; evalv[j + 1] = kv;
    }
}

// ---------------- bf16 path ----------------

// T0[m][n*64+f] = bf16(x[n][m][f])
__global__ void permute_bf16_kernel(const float* __restrict__ x, unsigned short* __restrict__ T0) {
    int idx = blockIdx.x * blockDim.x + threadIdx.x;   // M_*N_*16
    int f4 = idx & 15, n = (idx >> 4) & 7, m = idx >> 7;
    float4 v = ((const float4*)x)[(size_t)(n * M_ + m) * 16 + f4];
    ushort4 o;
    o.x = f2bf(v.x); o.y = f2bf(v.y); o.z = f2bf(v.z); o.w = f2bf(v.w);
    *(ushort4*)(T0 + (size_t)m * ROW_ + n * 64 + f4 * 4) = o;
}

static __device__ __forceinline__ void fma_u4(float* acc, float v, uint4 u) {
    acc[0] += v * bfl(u.x); acc[1] += v * bfh(u.x);
    acc[2] += v * bfl(u.y); acc[3] += v * bfh(u.y);
    acc[4] += v * bfl(u.z); acc[5] += v * bfh(u.z);
    acc[6] += v * bfl(u.w); acc[7] += v * bfh(u.w);
}

// nxt[m] = alpha*(L@cur)[m] + beta*prev[m]; wave w: row blockIdx*4+w, lane l: 16B chunk.
// 4-deep edge unroll for memory-level parallelism.
__global__ __launch_bounds__(256) void spmm_bf16_kernel(
        const unsigned short* __restrict__ cur, const unsigned short* __restrict__ prev,
        unsigned short* __restrict__ nxt,
        const int* __restrict__ rowptr, const int* __restrict__ ecol,
        const float* __restrict__ evalv, float alpha, float beta) {
    int t = threadIdx.x;
    int w = t >> 6, l = t & 63;
    int m = blockIdx.x * 4 + w;
    int s = rowptr[m], e = rowptr[m + 1];
    float acc[8] = {0.f, 0.f, 0.f, 0.f, 0.f, 0.f, 0.f, 0.f};
    int i = s;
    for (; i + 3 < e; i += 4) {
        int c0 = ecol[i], c1 = ecol[i+1], c2 = ecol[i+2], c3 = ecol[i+3];
        float v0 = evalv[i], v1 = evalv[i+1], v2 = evalv[i+2], v3 = evalv[i+3];
        uint4 u0 = *(const uint4*)(cur + (size_t)c0 * ROW_ + l * 8);
        uint4 u1 = *(const uint4*)(cur + (size_t)c1 * ROW_ + l * 8);
        uint4 u2 = *(const uint4*)(cur + (size_t)c2 * ROW_ + l * 8);
        uint4 u3 = *(const uint4*)(cur + (size_t)c3 * ROW_ + l * 8);
        fma_u4(acc, v0, u0); fma_u4(acc, v1, u1);
        fma_u4(acc, v2, u2); fma_u4(acc, v3, u3);
    }
    if (i + 1 < e) {
        int c0 = ecol[i], c1 = ecol[i+1];
        float v0 = evalv[i], v1 = evalv[i+1];
        uint4 u0 = *(const uint4*)(cur + (size_t)c0 * ROW_ + l * 8);
        uint4 u1 = *(const uint4*)(cur + (size_t)c1 * ROW_ + l * 8);
        fma_u4(acc, v0, u0); fma_u4(acc, v1, u1);
        i += 2;
    }
    if (i < e) {
        uint4 u0 = *(const uint4*)(cur + (size_t)ecol[i] * ROW_ + l * 8);
        fma_u4(acc, evalv[i], u0);
    }
    #pragma unroll
    for (int j = 0; j < 8; ++j) acc[j] *= alpha;
    if (beta != 0.f) {
        uint4 p = *(const uint4*)(prev + (size_t)m * ROW_ + l * 8);
        acc[0] += beta * bfl(p.x); acc[1] += beta * bfh(p.x);
        acc[2] += beta * bfl(p.y); acc[3] += beta * bfh(p.y);
        acc[4] += beta * bfl(p.z); acc[5] += beta * bfh(p.z);
        acc[6] += beta * bfl(p.w); acc[7] += beta * bfh(p.w);
    }
    uint4 o;
    o.x = (unsigned)f2bf(acc[0]) | ((unsigned)f2bf(acc[1]) << 16);
    o.y = (unsigned)f2bf(acc[2]) | ((unsigned)f2bf(acc[3]) << 16);
    o.z = (unsigned)f2bf(acc[4]) | ((unsigned)f2bf(acc[5]) << 16);
    o.w = (unsigned)f2bf(acc[6]) | ((unsigned)f2bf(acc[7]) << 16);
    *(uint4*)(nxt + (size_t)m * ROW_ + l * 8) = o;
}

// Wfrag[kk][tile][lane][i] = bf16(W[f*K+kcheb][tile*16 + lane%16]),
//   kcheb = kk>>1, f = (kk&1)*32 + (lane>>4)*8 + i   (B-fragment order for 16x16x32)
__global__ void wprep_kernel(const float* __restrict__ W, unsigned short* __restrict__ Wfrag) {
    int idx = blockIdx.x * blockDim.x + threadIdx.x;   // 24576
    int i = idx & 7, l = (idx >> 3) & 63, tile = (idx >> 9) & 3, kk = idx >> 11;
    int kcheb = kk >> 1;
    int f = (kk & 1) * 32 + (l >> 4) * 8 + i;
    int o = tile * 16 + (l & 15);
    Wfrag[idx] = f2bf(W[(f * K_ + kcheb) * OUT_ + o]);
}

static __device__ __forceinline__ void epilogue_tile(
        f32x4 acc, int tile, int rbase, int col,
        const float* __restrict__ bias, float* __restrict__ outn) {
    int c = tile * 16 + col;
    float b = bias[c];
    #pragma unroll
    for (int v = 0; v < 4; ++v) {
        float r = acc[v] + b;
        r = r > 0.f ? r : (__expf(r) - 1.f);
        outn[(size_t)(rbase + v) * OUT_ + c] = r;
    }
}

// out[n][m][o] = elu( sum_{k,f} T_k[m][n*64+f] * W[f*K+k][o] + bias[o] )
// grid M/32 blocks of 256. Block: 32 rows x all 8 n. W staged in LDS once.
// Wave w: row-half (w&1), n-half (w>>1) -> 4 independent n-iterations.
__global__ __launch_bounds__(256) void combine_kernel(
        const unsigned short* __restrict__ Tbase,   // 6 buffers, stride M_*ROW_
        const unsigned short* __restrict__ Wfrag,
        const float* __restrict__ bias, float* __restrict__ out) {
    __shared__ unsigned short wlds[24576];          // 48 KB
    int t = threadIdx.x;
    {
        const uint4* src = (const uint4*)Wfrag;
        uint4* dst = (uint4*)wlds;
        #pragma unroll
        for (int i = 0; i < 12; ++i)
            dst[t + 256 * i] = src[t + 256 * i];
    }
    __syncthreads();

    int w = t >> 6, l = t & 63;
    int rowhalf = w & 1, nhalf = w >> 1;
    int m0 = blockIdx.x * 32 + rowhalf * 16;
    int arow = m0 + (l & 15);
    const size_t MROW = (size_t)M_ * ROW_;
    size_t abase0 = (size_t)arow * ROW_ + (l >> 4) * 8;
    int rbase = m0 + (l >> 4) * 4;
    int col = l & 15;

    #pragma unroll
    for (int ni = 0; ni < 4; ++ni) {
        int n = nhalf * 4 + ni;
        size_t abase = abase0 + n * 64;
        bf16x8 a[12];
        #pragma unroll
        for (int kk = 0; kk < 12; ++kk)
            a[kk] = *(const bf16x8*)(Tbase + (size_t)(kk >> 1) * MROW + abase + (kk & 1) * 32);

        f32x4 acc0 = {0.f, 0.f, 0.f, 0.f};
        f32x4 acc1 = {0.f, 0.f, 0.f, 0.f};
        f32x4 acc2 = {0.f, 0.f, 0.f, 0.f};
        f32x4 acc3 = {0.f, 0.f, 0.f, 0.f};
        #pragma unroll
        for (int kk = 0; kk < 12; ++kk) {
            const unsigned short* wp = wlds + ((size_t)(kk * 4) * 64 + l) * 8;
            bf16x8 b0 = *(const bf16x8*)(wp);
            bf16x8 b1 = *(const bf16x8*)(wp + 512);
            bf16x8 b2 = *(const bf16x8*)(wp + 1024);
            bf16x8 b3 = *(const bf16x8*)(wp + 1536);
            acc0 = __builtin_amdgcn_mfma_f32_16x16x32_bf16(a[kk], b0, acc0, 0, 0, 0);
            acc1 = __builtin_amdgcn_mfma_f32_16x16x32_bf16(a[kk], b1, acc1, 0, 0, 0);
            acc2 = __builtin_amdgcn_mfma_f32_16x16x32_bf16(a[kk], b2, acc2, 0, 0, 0);
            acc3 = __builtin_amdgcn_mfma_f32_16x16x32_bf16(a[kk], b3, acc3, 0, 0, 0);
        }

        float* outn = out + (size_t)n * ((size_t)M_ * OUT_);
        epilogue_tile(acc0, 0, rbase, col, bias, outn);
        epilogue_tile(acc1, 1, rbase, col, bias, outn);
        epilogue_tile(acc2, 2, rbase, col, bias, outn);
        epilogue_tile(acc3, 3, rbase, col, bias, outn);
    }
}

// ---------------- Fallback f32 fused path ----------------

__global__ void permute_kernel(const float* __restrict__ x, float* __restrict__ A) {
    int idx = blockIdx.x * blockDim.x + threadIdx.x;
    int f4 = idx & 15;
    int n  = (idx >> 4) & 7;
    int m  = idx >> 7;
    float4 v = ((const float4*)x)[(size_t)(n * M_ + m) * 16 + f4];
    ((float4*)A)[idx] = v;
}

__global__ __launch_bounds__(512) void step_kernel(
        const float* __restrict__ cur, float* __restrict__ nxt,
        const float* __restrict__ weight, const float* __restrict__ bias,
        const int* __restrict__ rowptr, const int* __restrict__ ecol,
        const float* __restrict__ evalv, float* __restrict__ out,
        int k, float alpha, float beta, int flags) {
    __shared__ float lds_x[ROW_];
    int m = blockIdx.x;
    int t = threadIdx.x;
    lds_x[t] = cur[(size_t)m * ROW_ + t];
    if (flags & 4) {
        float acc = 0.f;
        int s = rowptr[m], e = rowptr[m + 1];
        for (int i = s; i < e; ++i)
            acc += evalv[i] * cur[(size_t)ecol[i] * ROW_ + t];
        float prevv = (beta != 0.f) ? nxt[(size_t)m * ROW_ + t] : 0.f;
        nxt[(size_t)m * ROW_ + t] = alpha * acc + beta * prevv;
    }
    __syncthreads();
    int n = t >> 6, o = t & 63;
    const float4* lx4 = (const float4*)(lds_x + n * FIN_);
    float acc = 0.f;
    #pragma unroll
    for (int f4 = 0; f4 < 16; ++f4) {
        float4 xq = lx4[f4];
        int fb = f4 * 4;
        acc += xq.x * weight[((fb + 0) * K_ + k) * OUT_ + o];
        acc += xq.y * weight[((fb + 1) * K_ + k) * OUT_ + o];
        acc += xq.z * weight[((fb + 2) * K_ + k) * OUT_ + o];
        acc += xq.w * weight[((fb + 3) * K_ + k) * OUT_ + o];
    }
    size_t oidx = (size_t)n * (M_ * OUT_) + (size_t)m * OUT_ + o;
    float res = (flags & 1) ? acc : (out[oidx] + acc);
    if (flags & 2) {
        res += bias[o];
        res = (res > 0.f) ? res : (expf(res) - 1.f);
    }
    out[oidx] = res;
}

// ---------------- launch ----------------

extern "C" void kernel_launch(void* const* d_in, const int* in_sizes, int n_in,
                              void* d_out, int out_size, void* d_ws, size_t ws_size,
                              hipStream_t stream) {
    (void)in_sizes; (void)n_in; (void)out_size;
    const float* x      = (const float*)d_in[0];
    const int*   rows   = (const int*)d_in[1];
    const int*   cols   = (const int*)d_in[2];
    const float* vals   = (const float*)d_in[3];
    const float* weight = (const float*)d_in[4];
    const float* bias   = (const float*)d_in[5];
    float* out = (float*)d_out;

    char* ws = (char*)d_ws;
    size_t off = 0;
    auto alloc = [&](size_t bytes) -> void* {
        void* p = ws + off;
        off += (bytes + 255) & ~(size_t)255;
        return p;
    };

    const size_t tbytes = (size_t)M_ * ROW_ * 2;          // 50.3 MB per bf16 T buffer
    const size_t need_new = 6 * (tbytes + 256) + (M_ + 1) * 4 + M_ * 4
                          + 3 * ((size_t)E_ * 4 + 256) + 24576 * 2 + 4096;

    if (ws_size >= need_new) {
        unsigned short* T[6];
        for (int i = 0; i < 6; ++i) T[i] = (unsigned short*)alloc(tbytes);
        int*   rowptr  = (int*)alloc((size_t)(M_ + 1) * 4);
        int*   fillpos = (int*)alloc((size_t)M_ * 4);
        int*   ecol    = (int*)alloc((size_t)E_ * 4);
        float* evalv   = (float*)alloc((size_t)E_ * 4);
        int*   eidx    = (int*)alloc((size_t)E_ * 4);
        unsigned short* Wfrag = (unsigned short*)alloc(24576 * 2);

        permute_bf16_kernel<<<(M_ * N_ * 16) / 256, 256, 0, stream>>>(x, T[0]);
        hipMemsetAsync(fillpos, 0, (size_t)M_ * 4, stream);
        count_kernel<<<E_ / 256, 256, 0, stream>>>(rows, fillpos);
        scan_kernel<<<1, 1024, 0, stream>>>(fillpos, rowptr);
        fill_kernel<<<E_ / 256, 256, 0, stream>>>(rows, cols, vals, fillpos, ecol, evalv, eidx);
        sort_kernel<<<M_ / 256, 256, 0, stream>>>(rowptr, ecol, evalv, eidx);
        wprep_kernel<<<96, 256, 0, stream>>>(weight, Wfrag);

        // T1 = L T0 ; Tk = 2 L T_{k-1} - T_{k-2}
        spmm_bf16_kernel<<<M_ / 4, 256, 0, stream>>>(T[0], T[0], T[1], rowptr, ecol, evalv, 1.f, 0.f);
        spmm_bf16_kernel<<<M_ / 4, 256, 0, stream>>>(T[1], T[0], T[2], rowptr, ecol, evalv, 2.f, -1.f);
        spmm_bf16_kernel<<<M_ / 4, 256, 0, stream>>>(T[2], T[1], T[3], rowptr, ecol, evalv, 2.f, -1.f);
        spmm_bf16_kernel<<<M_ / 4, 256, 0, stream>>>(T[3], T[2], T[4], rowptr, ecol, evalv, 2.f, -1.f);
        spmm_bf16_kernel<<<M_ / 4, 256, 0, stream>>>(T[4], T[3], T[5], rowptr, ecol, evalv, 2.f, -1.f);

        combine_kernel<<<M_ / 32, 256, 0, stream>>>(T[0], Wfrag, bias, out);
    } else {
        float* A       = (float*)alloc((size_t)M_ * ROW_ * 4);
        float* B       = (float*)alloc((size_t)M_ * ROW_ * 4);
        int*   rowptr  = (int*)alloc((size_t)(M_ + 1) * 4);
        int*   fillpos = (int*)alloc((size_t)M_ * 4);
        int*   ecol    = (int*)alloc((size_t)E_ * 4);
        float* evalv   = (float*)alloc((size_t)E_ * 4);
        int*   eidx    = (int*)alloc((size_t)E_ * 4);

        permute_kernel<<<(M_ * N_ * 16) / 256, 256, 0, stream>>>(x, A);
        hipMemsetAsync(fillpos, 0, (size_t)M_ * 4, stream);
        count_kernel<<<E_ / 256, 256, 0, stream>>>(rows, fillpos);
        scan_kernel<<<1, 1024, 0, stream>>>(fillpos, rowptr);
        fill_kernel<<<E_ / 256, 256, 0, stream>>>(rows, cols, vals, fillpos, ecol, evalv, eidx);
        sort_kernel<<<M_ / 256, 256, 0, stream>>>(rowptr, ecol, evalv, eidx);

        step_kernel<<<M_, 512, 0, stream>>>(A, B, weight, bias, rowptr, ecol, evalv, out, 0, 1.f, 0.f, 1 | 4);
        step_kernel<<<M_, 512, 0, stream>>>(B, A, weight, bias, rowptr, ecol, evalv, out, 1, 2.f, -1.f, 4);
        step_kernel<<<M_, 512, 0, stream>>>(A, B, weight, bias, rowptr, ecol, evalv, out, 2, 2.f, -1.f, 4);
        step_kernel<<<M_, 512, 0, stream>>>(B, A, weight, bias, rowptr, ecol, evalv, out, 3, 2.f, -1.f, 4);
        step_kernel<<<M_, 512, 0, stream>>>(A, B, weight, bias, rowptr, ecol, evalv, out, 4, 2.f, -1.f, 4);
        step_kernel<<<M_, 512, 0, stream>>>(B, B, weight, bias, rowptr, ecol, evalv, out, 5, 0.f, 0.f, 2);
    }
}